// Round 16
// baseline (113.492 us; speedup 1.0000x reference)
//
#include <hip/hip_runtime.h>

typedef __attribute__((ext_vector_type(8))) short short8;
typedef __attribute__((ext_vector_type(4))) float f32x4;
typedef __attribute__((ext_vector_type(16))) float f32x16;
typedef __attribute__((ext_vector_type(2))) unsigned int u32x2;
typedef __attribute__((ext_vector_type(4))) unsigned int u32x4;

#define DM 1024
#define SL 2048
#define NH 16
#define DKH 64
#define NB 2

__device__ __forceinline__ unsigned short f2bf(float f) {
    union { float f; unsigned int u; } a; a.f = f;
    unsigned int r = a.u + 0x7FFFu + ((a.u >> 16) & 1u);
    return (unsigned short)(r >> 16);
}

__device__ __forceinline__ void gl_lds16(const void* g, void* l) {
    __builtin_amdgcn_global_load_lds(
        (__attribute__((address_space(1))) void*)(g),
        (__attribute__((address_space(3))) void*)(l), 16, 0, 0);
}

__device__ __forceinline__ unsigned int cvtpk_bf16(float lo, float hi) {
    unsigned int r;
    asm("v_cvt_pk_bf16_f32 %0, %1, %2" : "=v"(r) : "v"(lo), "v"(hi));
    return r;
}

// v_permlane32_swap_b32 (m214-verified direction):
//   new_a[32:63] = old_b[0:31]; new_b[0:31] = old_a[32:63].
__device__ __forceinline__ void pl32swap(unsigned int &a, unsigned int &b) {
    u32x2 r = __builtin_amdgcn_permlane32_swap(a, b, false, false);
    a = r[0]; b = r[1];
}
__device__ __forceinline__ void pl32swapf(float &a, float &b) {
    unsigned int ua = __float_as_uint(a), ub = __float_as_uint(b);
    pl32swap(ua, ub);
    a = __uint_as_float(ua); b = __uint_as_float(ub);
}

// ---------------- fp32 -> bf16 conversion ---------------------------------------
// wq folded scale: 0.125 (1/sqrt(64)) * log2(e) so attention uses exp2 directly.
__global__ __launch_bounds__(256) void convert_kernel(
    const float* __restrict__ x,  const float* __restrict__ wq,
    const float* __restrict__ wk, const float* __restrict__ wv,
    const float* __restrict__ wo,
    unsigned short* __restrict__ xb,  unsigned short* __restrict__ wqb,
    unsigned short* __restrict__ wkb, unsigned short* __restrict__ wvb,
    unsigned short* __restrict__ wob)
{
    const int NX = NB * SL * DM;       // 4M
    const int NW = DM * DM;            // 1M
    int t4 = (blockIdx.x * 256 + threadIdx.x) * 4;
    const float* src; unsigned short* dst; int off; float scale = 1.0f;
    if (t4 < NX)              { src = x;  dst = xb;  off = t4; }
    else if (t4 < NX + NW)    { src = wq; dst = wqb; off = t4 - NX; scale = 0.125f * 1.44269504088896f; }
    else if (t4 < NX + 2*NW)  { src = wk; dst = wkb; off = t4 - NX - NW; }
    else if (t4 < NX + 3*NW)  { src = wv; dst = wvb; off = t4 - NX - 2*NW; }
    else                      { src = wo; dst = wob; off = t4 - NX - 3*NW; }
    float4 v = *(const float4*)(src + off);
    unsigned long long p =
        (unsigned long long)f2bf(v.x * scale)
      | ((unsigned long long)f2bf(v.y * scale) << 16)
      | ((unsigned long long)f2bf(v.z * scale) << 32)
      | ((unsigned long long)f2bf(v.w * scale) << 48);
    *(unsigned long long*)(dst + off) = p;
}

// ---------------- QKV GEMM  C[m][n] = sum_k A[m][k]*Bw[n][k]  (128x128, BK=64) --
__global__ __launch_bounds__(256) void gemm_bt(
    const unsigned short* __restrict__ A,
    const unsigned short* __restrict__ Bw,
    unsigned short* __restrict__ oq, unsigned short* __restrict__ ok,
    unsigned short* __restrict__ ov)
{
    __shared__ __align__(16) unsigned short As[128 * 64];
    __shared__ __align__(16) unsigned short Bs[128 * 64];
    const int tid  = threadIdx.x;
    const int lane = tid & 63;
    const int wave = tid >> 6;
    const int wm = (wave >> 1) * 64, wn = (wave & 1) * 64;
    const int bx = blockIdx.x, by = blockIdx.y;
    const int c    = lane & 15;
    const int kg16 = (lane >> 4) * 16;     // byte offset of k-subgroup
    const int swz  = (c & 7) << 4;

    f32x4 acc[4][4];
    #pragma unroll
    for (int i = 0; i < 4; i++)
        #pragma unroll
        for (int j = 0; j < 4; j++) acc[i][j] = (f32x4){0.f, 0.f, 0.f, 0.f};

    const char* Ab = (const char*)A  + by * 128 * (DM * 2);
    const char* Bb = (const char*)Bw + bx * 128 * (DM * 2);

    for (int k0 = 0; k0 < DM; k0 += 64) {
        #pragma unroll
        for (int i = 0; i < 4; i++) {
            int o  = i * 4096 + tid * 16;     // byte offset in 16KB tile
            int r  = o >> 7;                  // 128B per BK-row
            int cb = o & 127;
            int src = r * (DM * 2) + k0 * 2 + (cb ^ ((r & 7) << 4));
            gl_lds16(Ab + src, (char*)As + o);
            gl_lds16(Bb + src, (char*)Bs + o);
        }
        __syncthreads();
        #pragma unroll
        for (int kk = 0; kk < 2; kk++) {
            short8 a[4], bfr[4];
            #pragma unroll
            for (int mi = 0; mi < 4; mi++)
                a[mi] = *(const short8*)((const char*)As
                        + (wm + mi * 16 + c) * 128 + ((kk * 64 + kg16) ^ swz));
            #pragma unroll
            for (int ni = 0; ni < 4; ni++)
                bfr[ni] = *(const short8*)((const char*)Bs
                        + (wn + ni * 16 + c) * 128 + ((kk * 64 + kg16) ^ swz));
            #pragma unroll
            for (int mi = 0; mi < 4; mi++)
                #pragma unroll
                for (int ni = 0; ni < 4; ni++)
                    acc[mi][ni] = __builtin_amdgcn_mfma_f32_16x16x32_bf16(
                        a[mi], bfr[ni], acc[mi][ni], 0, 0, 0);
        }
        __syncthreads();
    }

    const int r4 = (lane >> 4) * 4;
    const int mat = (bx * 128) >> 10;                 // 0=q,1=k,2=v
    unsigned short* outb = (mat == 0) ? oq : (mat == 1) ? ok : ov;
    const int nb = bx * 128 - (mat << 10);
    #pragma unroll
    for (int mi = 0; mi < 4; mi++) {
        int m_g = by * 128 + wm + mi * 16 + r4;
        int b_  = m_g >> 11, s_ = m_g & 2047;
        #pragma unroll
        for (int ni = 0; ni < 4; ni++) {
            int n_l = nb + wn + ni * 16 + c;
            int h = n_l >> 6, dk = n_l & 63;
            #pragma unroll
            for (int j = 0; j < 4; j++)
                outb[((b_ * NH + h) * SL + (s_ + j)) * DKH + dk] = f2bf(acc[mi][ni][j]);
        }
    }
}

// ---------------- O GEMM (fused combine): 64x128 tiles, fp32 out ---------------
// Each A-tile (64 rows, 64 k-cols) maps to exactly ONE q-tile (rows 64-aligned)
// and ONE head (k0 64-aligned -> h = k0>>6). For qt>=16 tiles, A rows live in
// split-KV partials: A-stage reads partO rec pair + ml and combines in-register
// (same math as the old combine_kernel), writing the same linear LDS layout the
// gl_lds path produces. qt<16 tiles use gl_lds from Abf as before.
__global__ __launch_bounds__(256) void gemm_o(
    const unsigned short* __restrict__ A,     // Abf [4096][1024] (valid s<1024)
    const unsigned short* __restrict__ partO, // [1024 recs][64q][64d] bf16
    const float* __restrict__ ml,             // [1024 recs][64q][2] f32
    const unsigned short* __restrict__ Bw,    // [1024][1024] bf16
    float* __restrict__ of)                   // [4096][1024] fp32
{
    __shared__ __align__(16) unsigned short As[64 * 64];    // 8KB
    __shared__ __align__(16) unsigned short Bs[128 * 64];   // 16KB
    const int tid  = threadIdx.x;
    const int lane = tid & 63;
    const int wave = tid >> 6;
    const int wm = (wave >> 1) * 32, wn = (wave & 1) * 64;
    const int bx = blockIdx.x, by = blockIdx.y;   // bx: n-tile(8), by: m-tile(64)
    const int c    = lane & 15;
    const int kg16 = (lane >> 4) * 16;
    const int swz  = (c & 7) << 4;

    const int m0g  = by * 64;
    const int s_   = m0g & 2047;
    const int qt   = s_ >> 6;                 // 0..31
    const int bb   = m0g >> 11;
    const bool fuse = (qt >= 16);
    const int qtl  = qt - 16;

    f32x4 acc[2][4];
    #pragma unroll
    for (int i = 0; i < 2; i++)
        #pragma unroll
        for (int j = 0; j < 4; j++) acc[i][j] = (f32x4){0.f, 0.f, 0.f, 0.f};

    const char* Ab = (const char*)A  + by * 64  * (DM * 2);
    const char* Bb = (const char*)Bw + bx * 128 * (DM * 2);

    for (int k0 = 0; k0 < DM; k0 += 64) {
        if (!fuse) {
            #pragma unroll
            for (int i = 0; i < 2; i++) {
                int o  = i * 4096 + tid * 16;
                int r  = o >> 7, cb = o & 127;
                int src = r * (DM * 2) + k0 * 2 + (cb ^ ((r & 7) << 4));
                gl_lds16(Ab + src, (char*)As + o);
            }
        } else {
            const int h = k0 >> 6;
            const int rec0 = ((bb * 16 + h) * 16 + qtl) * 2;
            const char* p0 = (const char*)partO + (size_t)rec0 * 8192;
            const char* p1 = p0 + 8192;
            #pragma unroll
            for (int i = 0; i < 2; i++) {
                int o  = i * 4096 + tid * 16;
                int r  = o >> 7, cb = o & 127;
                int sco = r * 128 + (cb ^ ((r & 7) << 4));   // byte off in rec
                float m0v = ml[(rec0 * 64 + r) * 2];
                float l0v = ml[(rec0 * 64 + r) * 2 + 1];
                float m1v = ml[((rec0 + 1) * 64 + r) * 2];
                float l1v = ml[((rec0 + 1) * 64 + r) * 2 + 1];
                float M   = fmaxf(m0v, m1v);
                float w0  = __builtin_amdgcn_exp2f(m0v - M);
                float w1  = __builtin_amdgcn_exp2f(m1v - M);
                float inv = 1.0f / (w0 * l0v + w1 * l1v);
                float fw0 = w0 * inv, fw1 = w1 * inv;
                u32x4 u0 = *(const u32x4*)(p0 + sco);
                u32x4 u1 = *(const u32x4*)(p1 + sco);
                u32x4 ow;
                #pragma unroll
                for (int q = 0; q < 4; q++) {
                    unsigned int a0 = u0[q], a1 = u1[q];
                    float alo = __uint_as_float(a0 << 16);
                    float ahi = __uint_as_float(a0 & 0xFFFF0000u);
                    float clo = __uint_as_float(a1 << 16);
                    float chi = __uint_as_float(a1 & 0xFFFF0000u);
                    float rlo = alo * fw0 + clo * fw1;
                    float rhi = ahi * fw0 + chi * fw1;
                    ow[q] = cvtpk_bf16(rlo, rhi);
                }
                *(u32x4*)((char*)As + o) = ow;
            }
        }
        #pragma unroll
        for (int i = 0; i < 4; i++) {
            int o  = i * 4096 + tid * 16;
            int r  = o >> 7, cb = o & 127;
            int src = r * (DM * 2) + k0 * 2 + (cb ^ ((r & 7) << 4));
            gl_lds16(Bb + src, (char*)Bs + o);
        }
        __syncthreads();
        #pragma unroll
        for (int kk = 0; kk < 2; kk++) {
            short8 a[2], bfr[4];
            #pragma unroll
            for (int mi = 0; mi < 2; mi++)
                a[mi] = *(const short8*)((const char*)As
                        + (wm + mi * 16 + c) * 128 + ((kk * 64 + kg16) ^ swz));
            #pragma unroll
            for (int ni = 0; ni < 4; ni++)
                bfr[ni] = *(const short8*)((const char*)Bs
                        + (wn + ni * 16 + c) * 128 + ((kk * 64 + kg16) ^ swz));
            #pragma unroll
            for (int mi = 0; mi < 2; mi++)
                #pragma unroll
                for (int ni = 0; ni < 4; ni++)
                    acc[mi][ni] = __builtin_amdgcn_mfma_f32_16x16x32_bf16(
                        a[mi], bfr[ni], acc[mi][ni], 0, 0, 0);
        }
        __syncthreads();
    }

    const int r4 = (lane >> 4) * 4;
    #pragma unroll
    for (int mi = 0; mi < 2; mi++) {
        int m_g = by * 64 + wm + mi * 16 + r4;
        #pragma unroll
        for (int ni = 0; ni < 4; ni++) {
            int n_g = bx * 128 + wn + ni * 16 + c;
            #pragma unroll
            for (int j = 0; j < 4; j++)
                of[(m_g + j) * DM + n_g] = acc[mi][ni][j];
        }
    }
}

// ---------------- causal flash attention: split-KV, swapped-QK^T 32x32 ---------
// r15 measured-best (45.4us, Vt conflict-fixed). Work item = (bh, qt, chunk).
// qt<16: single chunk, direct write to Abf. qt>=16: 2 chunks -> partial
// (partO+ml); the fused gemm_o combines them. id = item*32 + bh.
__global__ __launch_bounds__(128) void attn_kernel(
    const unsigned short* __restrict__ Q,   // [B*H][S][64] bf16 (pre-scaled)
    const unsigned short* __restrict__ K,
    const unsigned short* __restrict__ V,
    unsigned short* __restrict__ O,         // [B*S][1024] bf16 head-concat
    unsigned short* __restrict__ partO,     // [1024 recs][64q][64d] bf16
    float* __restrict__ ml)                 // [1024 recs][64q][2] f32
{
    __shared__ __align__(16) unsigned short Kl[2][64 * 64];    // 8KB each
    __shared__ __align__(16) unsigned short Vt[2][8 * 64 * 8]; // 8KB each
    const int tid = threadIdx.x, lane = tid & 63, wave = tid >> 6;
    const int ln31 = lane & 31, hi = lane >> 5;
    const int item = blockIdx.x >> 5;
    const int bh   = blockIdx.x & 31;
    int qt, cch, t0, ntc;
    if (item < 16)      { qt = 16 + item;              cch = 0; t0 = 0;  ntc = 16; }
    else if (item < 32) { int j = item - 16; qt = 31 - j; cch = 1; t0 = 16; ntc = 16 - j; }
    else                { int j = item - 32; qt = 15 - j; cch = 0; t0 = 0;  ntc = 16 - j; }
    const int b = bh >> 4, h = bh & 15;
    const int bhi = b * NH + h;
    const unsigned short* Qg = Q + bhi * (SL * DKH);
    const unsigned short* Kg = K + bhi * (SL * DKH);
    const unsigned short* Vg = V + bhi * (SL * DKH);
    const int qw = qt * 64 + wave * 32;
    const int vd0 = (tid & 31) * 2, c0 = tid >> 5;   // V stage mapping
    const int vsw = (vd0 >> 3) & 1;                  // write-side XOR bit
    const int rsw = (ln31 >> 3) & 1;                 // read-side XOR bit

    // Q B-fragments: lane holds Q[qw+ln31][ks*16 + hi*8 .. +7]
    short8 qf[4];
    #pragma unroll
    for (int ks = 0; ks < 4; ks++)
        qf[ks] = *(const short8*)&Qg[(qw + ln31) * DKH + ks * 16 + hi * 8];

    f32x16 OT0, OT1;
    #pragma unroll
    for (int r = 0; r < 16; r++) { OT0[r] = 0.f; OT1[r] = 0.f; }
    float mrun = -1e30f, ls = 0.f;

    unsigned int vreg[16];

    // prologue: stage tile t0
    {
        const size_t kvb = (size_t)t0 * 64;
        #pragma unroll
        for (int i = 0; i < 4; i++) {
            int s = i * 128 + tid;          // 0..511 16B-chunks of 8KB tile
            int kv = s >> 3;
            int k8 = (s & 7) ^ (kv & 7);
            gl_lds16((const char*)Kg + (kvb + kv) * 128 + k8 * 16,
                     (char*)&Kl[0][0] + s * 16);
        }
        #pragma unroll
        for (int c2 = 0; c2 < 2; c2++)
            #pragma unroll
            for (int i = 0; i < 8; i++)
                vreg[c2 * 8 + i] = *(const unsigned int*)&Vg[(kvb + (c0 + 4 * c2) * 8 + i) * DKH + vd0];
    }

    for (int tt = 0; tt < ntc; ++tt) {
        const int t = t0 + tt;
        const int buf = tt & 1;
        const int kv0 = t * 64;
        // write staged V regs -> Vt[buf], subtile layout [chunk][d][8] (XOR-swz)
        #pragma unroll
        for (int c2 = 0; c2 < 2; c2++) {
            int chunk = c0 + 4 * c2;
            short8 sa, sb;
            #pragma unroll
            for (int i = 0; i < 8; i++) {
                unsigned int pr = vreg[c2 * 8 + i];
                sa[i] = (short)(pr & 0xFFFFu);
                sb[i] = (short)(pr >> 16);
            }
            int ua = chunk * 64 + vd0;               // even 16B-unit index
            *(short8*)&Vt[buf][(ua ^ vsw) * 8]       = sa;
            *(short8*)&Vt[buf][((ua + 1) ^ vsw) * 8] = sb;
        }
        __syncthreads();   // drains gl_lds for Kl[buf]; Vt[buf] visible

        if (tt + 1 < ntc) {   // prefetch next tile under this compute
            const size_t kv1 = (size_t)(t + 1) * 64;
            #pragma unroll
            for (int i = 0; i < 4; i++) {
                int s = i * 128 + tid;
                int kv = s >> 3;
                int k8 = (s & 7) ^ (kv & 7);
                gl_lds16((const char*)Kg + (kv1 + kv) * 128 + k8 * 16,
                         (char*)&Kl[buf ^ 1][0] + s * 16);
            }
            #pragma unroll
            for (int c2 = 0; c2 < 2; c2++)
                #pragma unroll
                for (int i = 0; i < 8; i++)
                    vreg[c2 * 8 + i] = *(const unsigned int*)&Vg[(kv1 + (c0 + 4 * c2) * 8 + i) * DKH + vd0];
        }

        const char* kb = (const char*)&Kl[buf][0];
        const unsigned short* vb = &Vt[buf][0];

        // S^T = K . Q^T : two 32-kv subtiles
        f32x16 S0, S1;
        #pragma unroll
        for (int r = 0; r < 16; r++) { S0[r] = 0.f; S1[r] = 0.f; }
        __builtin_amdgcn_s_setprio(1);
        #pragma unroll
        for (int ks = 0; ks < 4; ks++) {
            int ko = (ks * 32 + hi * 16) ^ ((ln31 & 7) << 4);
            short8 ka0 = *(const short8*)(kb + ln31 * 128 + ko);
            short8 ka1 = *(const short8*)(kb + (32 + ln31) * 128 + ko);
            S0 = __builtin_amdgcn_mfma_f32_32x32x16_bf16(ka0, qf[ks], S0, 0, 0, 0);
            S1 = __builtin_amdgcn_mfma_f32_32x32x16_bf16(ka1, qf[ks], S1, 0, 0, 0);
        }
        __builtin_amdgcn_s_setprio(0);

        // causal mask: only the diagonal tile (t == qt)
        if (t == qt) {
            const int qrel0 = qw + ln31 - kv0 - 4 * hi;
            const int qrel1 = qrel0 - 32;
            #pragma unroll
            for (int r = 0; r < 16; r++) {
                const int ro = (r & 3) + 8 * (r >> 2);
                if (ro > qrel0) S0[r] = -1e30f;
                if (ro > qrel1) S1[r] = -1e30f;
            }
        }

        // row max: in-reg tree + 1 permlane swap
        float mx = fmaxf(S0[0], S1[0]);
        #pragma unroll
        for (int r = 1; r < 16; r++) mx = fmaxf(mx, fmaxf(S0[r], S1[r]));
        float ma = mx, mb = mx;
        pl32swapf(ma, mb);
        float rm = fmaxf(ma, mb);

        // defer-max rescale (THR=8 in log2 units)
        if (__any(rm > mrun + 8.f)) {
            float nm = fmaxf(mrun, rm);
            float corr = __builtin_amdgcn_exp2f(mrun - nm);
            mrun = nm; ls *= corr;
            #pragma unroll
            for (int r = 0; r < 16; r++) { OT0[r] *= corr; OT1[r] *= corr; }
        }

        // P = exp2(S - m) in place (bare v_exp_f32); per-lane half-row sum
        float psum = 0.f;
        #pragma unroll
        for (int r = 0; r < 16; r++) {
            S0[r] = __builtin_amdgcn_exp2f(S0[r] - mrun); psum += S0[r];
            S1[r] = __builtin_amdgcn_exp2f(S1[r] - mrun); psum += S1[r];
        }
        ls += psum;

        // build P B-fragments in-register (T12, m214-verified ordering)
        short8 pf[4];
        {
            unsigned int wa, wb, wc, wd;
            wa = cvtpk_bf16(S0[0], S0[1]);   wb = cvtpk_bf16(S0[4], S0[5]);
            pl32swap(wa, wb);
            wc = cvtpk_bf16(S0[2], S0[3]);   wd = cvtpk_bf16(S0[6], S0[7]);
            pl32swap(wc, wd);
            union { unsigned int u[4]; short8 s; } w0 = {{wa, wc, wb, wd}};
            pf[0] = w0.s;

            wa = cvtpk_bf16(S0[8], S0[9]);   wb = cvtpk_bf16(S0[12], S0[13]);
            pl32swap(wa, wb);
            wc = cvtpk_bf16(S0[10], S0[11]); wd = cvtpk_bf16(S0[14], S0[15]);
            pl32swap(wc, wd);
            union { unsigned int u[4]; short8 s; } w1 = {{wa, wc, wb, wd}};
            pf[1] = w1.s;

            wa = cvtpk_bf16(S1[0], S1[1]);   wb = cvtpk_bf16(S1[4], S1[5]);
            pl32swap(wa, wb);
            wc = cvtpk_bf16(S1[2], S1[3]);   wd = cvtpk_bf16(S1[6], S1[7]);
            pl32swap(wc, wd);
            union { unsigned int u[4]; short8 s; } w2 = {{wa, wc, wb, wd}};
            pf[2] = w2.s;

            wa = cvtpk_bf16(S1[8], S1[9]);   wb = cvtpk_bf16(S1[12], S1[13]);
            pl32swap(wa, wb);
            wc = cvtpk_bf16(S1[10], S1[11]); wd = cvtpk_bf16(S1[14], S1[15]);
            pl32swap(wc, wd);
            union { unsigned int u[4]; short8 s; } w3 = {{wa, wc, wb, wd}};
            pf[3] = w3.s;
        }

        // O^T += V^T . P  (A = V^T from subtiled Vt, B = P in-reg; XOR-swz reads)
        __builtin_amdgcn_s_setprio(1);
        #pragma unroll
        for (int ks2 = 0; ks2 < 4; ks2++) {
            int slot = (ks2 * 2 + hi) * 64;
            int r0u = slot + ln31;
            int r1u = slot + 32 + ln31;
            short8 va0 = *(const short8*)&vb[(r0u ^ rsw) * 8];
            short8 va1 = *(const short8*)&vb[(r1u ^ rsw) * 8];
            OT0 = __builtin_amdgcn_mfma_f32_32x32x16_bf16(va0, pf[ks2], OT0, 0, 0, 0);
            OT1 = __builtin_amdgcn_mfma_f32_32x32x16_bf16(va1, pf[ks2], OT1, 0, 0, 0);
        }
        __builtin_amdgcn_s_setprio(0);
    }

    // epilogue
    float la = ls, lb = ls;
    pl32swapf(la, lb);
    const float lrow = la + lb;
    const int qrow_l = wave * 32 + ln31;
    if (qt >= 16) {
        // partial: unnormalized O (bf16) + m,l (f32)
        const int rec = (bh * 16 + (qt - 16)) * 2 + cch;
        unsigned short* po = partO + (size_t)rec * 4096;
        if (hi == 0) {
            ml[(rec * 64 + qrow_l) * 2]     = mrun;
            ml[(rec * 64 + qrow_l) * 2 + 1] = lrow;
        }
        #pragma unroll
        for (int r = 0; r < 16; r++) {
            const int d0 = (r & 3) + 8 * (r >> 2) + 4 * hi;
            po[qrow_l * 64 + d0]      = f2bf(OT0[r]);
            po[qrow_l * 64 + 32 + d0] = f2bf(OT1[r]);
        }
    } else {
        float inv = 1.0f / lrow;
        const int qrow = qw + ln31;
        const size_t base = (size_t)(b * SL + qrow) * DM + h * DKH;
        #pragma unroll
        for (int r = 0; r < 16; r++) {
            const int d0 = (r & 3) + 8 * (r >> 2) + 4 * hi;
            O[base + d0]      = f2bf(OT0[r] * inv);
            O[base + 32 + d0] = f2bf(OT1[r] * inv);
        }
    }
}

// ---------------- launch -------------------------------------------------------
extern "C" void kernel_launch(void* const* d_in, const int* in_sizes, int n_in,
                              void* d_out, int out_size, void* d_ws, size_t ws_size,
                              hipStream_t stream)
{
    const float* x  = (const float*)d_in[0];
    const float* wq = (const float*)d_in[1];
    const float* wk = (const float*)d_in[2];
    const float* wv = (const float*)d_in[3];
    const float* wo = (const float*)d_in[4];
    char* ws = (char*)d_ws;
    unsigned short* xb  = (unsigned short*)(ws);                        // 8MB
    unsigned short* wqb = (unsigned short*)(ws + (8ll  << 20));         // 2MB (wq,wk,wv contiguous)
    unsigned short* wkb = (unsigned short*)(ws + (10ll << 20));
    unsigned short* wvb = (unsigned short*)(ws + (12ll << 20));
    unsigned short* wob = (unsigned short*)(ws + (14ll << 20));
    unsigned short* Qb  = (unsigned short*)(ws + (16ll << 20));         // 8MB each
    unsigned short* Kb  = (unsigned short*)(ws + (24ll << 20));
    unsigned short* Vb  = (unsigned short*)(ws + (32ll << 20));
    unsigned short* Abf = (unsigned short*)(ws + (40ll << 20));         // 8MB
    // attn scratch reuses [0,10MB): dead after the QKV GEMM consumes xb/wqb
    unsigned short* partO = (unsigned short*)(ws);                      // 8MB (1024 recs x 8KB)
    float*          mlbuf = (float*)(ws + (8ll << 20));                 // 512KB
    float* out = (float*)d_out;

    convert_kernel<<<dim3(8192), dim3(256), 0, stream>>>(
        x, wq, wk, wv, wo, xb, wqb, wkb, wvb, wob);

    // fused QKV projection: N = 3072 (wqb/wkb/wvb contiguous)
    gemm_bt<<<dim3(24, 32), dim3(256), 0, stream>>>(xb, wqb, Qb, Kb, Vb);

    // split-KV attention: 48 items x 32 bh, LPT-ordered static grid
    attn_kernel<<<dim3(1536), dim3(128), 0, stream>>>(Qb, Kb, Vb, Abf, partO, mlbuf);

    // output projection with fused split-KV combine -> fp32 d_out
    gemm_o<<<dim3(8, 64), dim3(256), 0, stream>>>(Abf, partO, mlbuf, wob, out);
}

// Round 17
// 104.742 us; speedup vs baseline: 1.0835x; 1.0835x over previous
//
#include <hip/hip_runtime.h>

typedef __attribute__((ext_vector_type(8))) short short8;
typedef __attribute__((ext_vector_type(4))) float f32x4;
typedef __attribute__((ext_vector_type(16))) float f32x16;
typedef __attribute__((ext_vector_type(2))) unsigned int u32x2;

#define DM 1024
#define SL 2048
#define NH 16
#define DKH 64
#define NB 2

__device__ __forceinline__ unsigned short f2bf(float f) {
    union { float f; unsigned int u; } a; a.f = f;
    unsigned int r = a.u + 0x7FFFu + ((a.u >> 16) & 1u);
    return (unsigned short)(r >> 16);
}

__device__ __forceinline__ void gl_lds16(const void* g, void* l) {
    __builtin_amdgcn_global_load_lds(
        (__attribute__((address_space(1))) void*)(g),
        (__attribute__((address_space(3))) void*)(l), 16, 0, 0);
}

__device__ __forceinline__ unsigned int cvtpk_bf16(float lo, float hi) {
    unsigned int r;
    asm("v_cvt_pk_bf16_f32 %0, %1, %2" : "=v"(r) : "v"(lo), "v"(hi));
    return r;
}

// v_permlane32_swap_b32 (m214-verified direction):
//   new_a[32:63] = old_b[0:31]; new_b[0:31] = old_a[32:63].
__device__ __forceinline__ void pl32swap(unsigned int &a, unsigned int &b) {
    u32x2 r = __builtin_amdgcn_permlane32_swap(a, b, false, false);
    a = r[0]; b = r[1];
}
__device__ __forceinline__ void pl32swapf(float &a, float &b) {
    unsigned int ua = __float_as_uint(a), ub = __float_as_uint(b);
    pl32swap(ua, ub);
    a = __uint_as_float(ua); b = __uint_as_float(ub);
}

// ---------------- fp32 -> bf16 conversion ---------------------------------------
// wq folded scale: 0.125 (1/sqrt(64)) * log2(e) so attention uses exp2 directly.
__global__ __launch_bounds__(256) void convert_kernel(
    const float* __restrict__ x,  const float* __restrict__ wq,
    const float* __restrict__ wk, const float* __restrict__ wv,
    const float* __restrict__ wo,
    unsigned short* __restrict__ xb,  unsigned short* __restrict__ wqb,
    unsigned short* __restrict__ wkb, unsigned short* __restrict__ wvb,
    unsigned short* __restrict__ wob)
{
    const int NX = NB * SL * DM;       // 4M
    const int NW = DM * DM;            // 1M
    int t4 = (blockIdx.x * 256 + threadIdx.x) * 4;
    const float* src; unsigned short* dst; int off; float scale = 1.0f;
    if (t4 < NX)              { src = x;  dst = xb;  off = t4; }
    else if (t4 < NX + NW)    { src = wq; dst = wqb; off = t4 - NX; scale = 0.125f * 1.44269504088896f; }
    else if (t4 < NX + 2*NW)  { src = wk; dst = wkb; off = t4 - NX - NW; }
    else if (t4 < NX + 3*NW)  { src = wv; dst = wvb; off = t4 - NX - 2*NW; }
    else                      { src = wo; dst = wob; off = t4 - NX - 3*NW; }
    float4 v = *(const float4*)(src + off);
    unsigned long long p =
        (unsigned long long)f2bf(v.x * scale)
      | ((unsigned long long)f2bf(v.y * scale) << 16)
      | ((unsigned long long)f2bf(v.z * scale) << 32)
      | ((unsigned long long)f2bf(v.w * scale) << 48);
    *(unsigned long long*)(dst + off) = p;
}

// ---------------- QKV GEMM  C[m][n] = sum_k A[m][k]*Bw[n][k]  (128x128, BK=64) --
__global__ __launch_bounds__(256) void gemm_bt(
    const unsigned short* __restrict__ A,
    const unsigned short* __restrict__ Bw,
    unsigned short* __restrict__ oq, unsigned short* __restrict__ ok,
    unsigned short* __restrict__ ov)
{
    __shared__ __align__(16) unsigned short As[128 * 64];
    __shared__ __align__(16) unsigned short Bs[128 * 64];
    const int tid  = threadIdx.x;
    const int lane = tid & 63;
    const int wave = tid >> 6;
    const int wm = (wave >> 1) * 64, wn = (wave & 1) * 64;
    const int bx = blockIdx.x, by = blockIdx.y;
    const int c    = lane & 15;
    const int kg16 = (lane >> 4) * 16;     // byte offset of k-subgroup
    const int swz  = (c & 7) << 4;

    f32x4 acc[4][4];
    #pragma unroll
    for (int i = 0; i < 4; i++)
        #pragma unroll
        for (int j = 0; j < 4; j++) acc[i][j] = (f32x4){0.f, 0.f, 0.f, 0.f};

    const char* Ab = (const char*)A  + by * 128 * (DM * 2);
    const char* Bb = (const char*)Bw + bx * 128 * (DM * 2);

    for (int k0 = 0; k0 < DM; k0 += 64) {
        #pragma unroll
        for (int i = 0; i < 4; i++) {
            int o  = i * 4096 + tid * 16;     // byte offset in 16KB tile
            int r  = o >> 7;                  // 128B per BK-row
            int cb = o & 127;
            int src = r * (DM * 2) + k0 * 2 + (cb ^ ((r & 7) << 4));
            gl_lds16(Ab + src, (char*)As + o);
            gl_lds16(Bb + src, (char*)Bs + o);
        }
        __syncthreads();
        #pragma unroll
        for (int kk = 0; kk < 2; kk++) {
            short8 a[4], bfr[4];
            #pragma unroll
            for (int mi = 0; mi < 4; mi++)
                a[mi] = *(const short8*)((const char*)As
                        + (wm + mi * 16 + c) * 128 + ((kk * 64 + kg16) ^ swz));
            #pragma unroll
            for (int ni = 0; ni < 4; ni++)
                bfr[ni] = *(const short8*)((const char*)Bs
                        + (wn + ni * 16 + c) * 128 + ((kk * 64 + kg16) ^ swz));
            #pragma unroll
            for (int mi = 0; mi < 4; mi++)
                #pragma unroll
                for (int ni = 0; ni < 4; ni++)
                    acc[mi][ni] = __builtin_amdgcn_mfma_f32_16x16x32_bf16(
                        a[mi], bfr[ni], acc[mi][ni], 0, 0, 0);
        }
        __syncthreads();
    }

    const int r4 = (lane >> 4) * 4;
    const int mat = (bx * 128) >> 10;                 // 0=q,1=k,2=v
    unsigned short* outb = (mat == 0) ? oq : (mat == 1) ? ok : ov;
    const int nb = bx * 128 - (mat << 10);
    #pragma unroll
    for (int mi = 0; mi < 4; mi++) {
        int m_g = by * 128 + wm + mi * 16 + r4;
        int b_  = m_g >> 11, s_ = m_g & 2047;
        #pragma unroll
        for (int ni = 0; ni < 4; ni++) {
            int n_l = nb + wn + ni * 16 + c;
            int h = n_l >> 6, dk = n_l & 63;
            #pragma unroll
            for (int j = 0; j < 4; j++)
                outb[((b_ * NH + h) * SL + (s_ + j)) * DKH + dk] = f2bf(acc[mi][ni][j]);
        }
    }
}

// ---------------- O GEMM: 64x128 tiles, fp32 out (512 blocks = 2/CU) -----------
__global__ __launch_bounds__(256) void gemm_o(
    const unsigned short* __restrict__ A,    // [4096][1024] bf16
    const unsigned short* __restrict__ Bw,   // [1024][1024] bf16
    float* __restrict__ of)                  // [4096][1024] fp32
{
    __shared__ __align__(16) unsigned short As[64 * 64];    // 8KB
    __shared__ __align__(16) unsigned short Bs[128 * 64];   // 16KB
    const int tid  = threadIdx.x;
    const int lane = tid & 63;
    const int wave = tid >> 6;
    const int wm = (wave >> 1) * 32, wn = (wave & 1) * 64;
    const int bx = blockIdx.x, by = blockIdx.y;   // bx: n-tile(8), by: m-tile(64)
    const int c    = lane & 15;
    const int kg16 = (lane >> 4) * 16;
    const int swz  = (c & 7) << 4;

    f32x4 acc[2][4];
    #pragma unroll
    for (int i = 0; i < 2; i++)
        #pragma unroll
        for (int j = 0; j < 4; j++) acc[i][j] = (f32x4){0.f, 0.f, 0.f, 0.f};

    const char* Ab = (const char*)A  + by * 64  * (DM * 2);
    const char* Bb = (const char*)Bw + bx * 128 * (DM * 2);

    for (int k0 = 0; k0 < DM; k0 += 64) {
        #pragma unroll
        for (int i = 0; i < 2; i++) {
            int o  = i * 4096 + tid * 16;
            int r  = o >> 7, cb = o & 127;
            int src = r * (DM * 2) + k0 * 2 + (cb ^ ((r & 7) << 4));
            gl_lds16(Ab + src, (char*)As + o);
        }
        #pragma unroll
        for (int i = 0; i < 4; i++) {
            int o  = i * 4096 + tid * 16;
            int r  = o >> 7, cb = o & 127;
            int src = r * (DM * 2) + k0 * 2 + (cb ^ ((r & 7) << 4));
            gl_lds16(Bb + src, (char*)Bs + o);
        }
        __syncthreads();
        #pragma unroll
        for (int kk = 0; kk < 2; kk++) {
            short8 a[2], bfr[4];
            #pragma unroll
            for (int mi = 0; mi < 2; mi++)
                a[mi] = *(const short8*)((const char*)As
                        + (wm + mi * 16 + c) * 128 + ((kk * 64 + kg16) ^ swz));
            #pragma unroll
            for (int ni = 0; ni < 4; ni++)
                bfr[ni] = *(const short8*)((const char*)Bs
                        + (wn + ni * 16 + c) * 128 + ((kk * 64 + kg16) ^ swz));
            #pragma unroll
            for (int mi = 0; mi < 2; mi++)
                #pragma unroll
                for (int ni = 0; ni < 4; ni++)
                    acc[mi][ni] = __builtin_amdgcn_mfma_f32_16x16x32_bf16(
                        a[mi], bfr[ni], acc[mi][ni], 0, 0, 0);
        }
        __syncthreads();
    }

    const int r4 = (lane >> 4) * 4;
    #pragma unroll
    for (int mi = 0; mi < 2; mi++) {
        int m_g = by * 64 + wm + mi * 16 + r4;
        #pragma unroll
        for (int ni = 0; ni < 4; ni++) {
            int n_g = bx * 128 + wn + ni * 16 + c;
            #pragma unroll
            for (int j = 0; j < 4; j++)
                of[(m_g + j) * DM + n_g] = acc[mi][ni][j];
        }
    }
}

// ---------------- causal flash attention: split-KV, swapped-QK^T 32x32 ---------
// Measured-best structure (45.2-45.4us): static LPT split-KV grid, gl_lds K
// dbuf + reg-V dbuf, swapped QK^T, in-reg P via cvt_pk+permlane, defer-max,
// Vt XOR-swizzle (both sides; conflicts 2.16M->1.08M).
// Work item = (bh, qt, chunk). qt<16: single chunk, direct write. qt>=16:
// 2 chunks -> partial (partO+ml); combine_kernel merges. id = item*32 + bh.
__global__ __launch_bounds__(128) void attn_kernel(
    const unsigned short* __restrict__ Q,   // [B*H][S][64] bf16 (pre-scaled)
    const unsigned short* __restrict__ K,
    const unsigned short* __restrict__ V,
    unsigned short* __restrict__ O,         // [B*S][1024] bf16 head-concat
    unsigned short* __restrict__ partO,     // [1024 recs][64q][64d] bf16
    float* __restrict__ ml)                 // [1024 recs][64q][2] f32
{
    __shared__ __align__(16) unsigned short Kl[2][64 * 64];    // 8KB each
    __shared__ __align__(16) unsigned short Vt[2][8 * 64 * 8]; // 8KB each
    const int tid = threadIdx.x, lane = tid & 63, wave = tid >> 6;
    const int ln31 = lane & 31, hi = lane >> 5;
    const int item = blockIdx.x >> 5;
    const int bh   = blockIdx.x & 31;
    int qt, cch, t0, ntc;
    if (item < 16)      { qt = 16 + item;              cch = 0; t0 = 0;  ntc = 16; }
    else if (item < 32) { int j = item - 16; qt = 31 - j; cch = 1; t0 = 16; ntc = 16 - j; }
    else                { int j = item - 32; qt = 15 - j; cch = 0; t0 = 0;  ntc = 16 - j; }
    const int b = bh >> 4, h = bh & 15;
    const int bhi = b * NH + h;
    const unsigned short* Qg = Q + bhi * (SL * DKH);
    const unsigned short* Kg = K + bhi * (SL * DKH);
    const unsigned short* Vg = V + bhi * (SL * DKH);
    const int qw = qt * 64 + wave * 32;
    const int vd0 = (tid & 31) * 2, c0 = tid >> 5;   // V stage mapping
    const int vsw = (vd0 >> 3) & 1;                  // write-side XOR bit
    const int rsw = (ln31 >> 3) & 1;                 // read-side XOR bit

    // Q B-fragments: lane holds Q[qw+ln31][ks*16 + hi*8 .. +7]
    short8 qf[4];
    #pragma unroll
    for (int ks = 0; ks < 4; ks++)
        qf[ks] = *(const short8*)&Qg[(qw + ln31) * DKH + ks * 16 + hi * 8];

    f32x16 OT0, OT1;
    #pragma unroll
    for (int r = 0; r < 16; r++) { OT0[r] = 0.f; OT1[r] = 0.f; }
    float mrun = -1e30f, ls = 0.f;

    unsigned int vreg[16];

    // prologue: stage tile t0
    {
        const size_t kvb = (size_t)t0 * 64;
        #pragma unroll
        for (int i = 0; i < 4; i++) {
            int s = i * 128 + tid;          // 0..511 16B-chunks of 8KB tile
            int kv = s >> 3;
            int k8 = (s & 7) ^ (kv & 7);
            gl_lds16((const char*)Kg + (kvb + kv) * 128 + k8 * 16,
                     (char*)&Kl[0][0] + s * 16);
        }
        #pragma unroll
        for (int c2 = 0; c2 < 2; c2++)
            #pragma unroll
            for (int i = 0; i < 8; i++)
                vreg[c2 * 8 + i] = *(const unsigned int*)&Vg[(kvb + (c0 + 4 * c2) * 8 + i) * DKH + vd0];
    }

    for (int tt = 0; tt < ntc; ++tt) {
        const int t = t0 + tt;
        const int buf = tt & 1;
        const int kv0 = t * 64;
        // write staged V regs -> Vt[buf], subtile layout [chunk][d][8] (XOR-swz)
        #pragma unroll
        for (int c2 = 0; c2 < 2; c2++) {
            int chunk = c0 + 4 * c2;
            short8 sa, sb;
            #pragma unroll
            for (int i = 0; i < 8; i++) {
                unsigned int pr = vreg[c2 * 8 + i];
                sa[i] = (short)(pr & 0xFFFFu);
                sb[i] = (short)(pr >> 16);
            }
            int ua = chunk * 64 + vd0;               // even 16B-unit index
            *(short8*)&Vt[buf][(ua ^ vsw) * 8]       = sa;
            *(short8*)&Vt[buf][((ua + 1) ^ vsw) * 8] = sb;
        }
        __syncthreads();   // drains gl_lds for Kl[buf]; Vt[buf] visible

        if (tt + 1 < ntc) {   // prefetch next tile under this compute
            const size_t kv1 = (size_t)(t + 1) * 64;
            #pragma unroll
            for (int i = 0; i < 4; i++) {
                int s = i * 128 + tid;
                int kv = s >> 3;
                int k8 = (s & 7) ^ (kv & 7);
                gl_lds16((const char*)Kg + (kv1 + kv) * 128 + k8 * 16,
                         (char*)&Kl[buf ^ 1][0] + s * 16);
            }
            #pragma unroll
            for (int c2 = 0; c2 < 2; c2++)
                #pragma unroll
                for (int i = 0; i < 8; i++)
                    vreg[c2 * 8 + i] = *(const unsigned int*)&Vg[(kv1 + (c0 + 4 * c2) * 8 + i) * DKH + vd0];
        }

        const char* kb = (const char*)&Kl[buf][0];
        const unsigned short* vb = &Vt[buf][0];

        // S^T = K . Q^T : two 32-kv subtiles
        f32x16 S0, S1;
        #pragma unroll
        for (int r = 0; r < 16; r++) { S0[r] = 0.f; S1[r] = 0.f; }
        __builtin_amdgcn_s_setprio(1);
        #pragma unroll
        for (int ks = 0; ks < 4; ks++) {
            int ko = (ks * 32 + hi * 16) ^ ((ln31 & 7) << 4);
            short8 ka0 = *(const short8*)(kb + ln31 * 128 + ko);
            short8 ka1 = *(const short8*)(kb + (32 + ln31) * 128 + ko);
            S0 = __builtin_amdgcn_mfma_f32_32x32x16_bf16(ka0, qf[ks], S0, 0, 0, 0);
            S1 = __builtin_amdgcn_mfma_f32_32x32x16_bf16(ka1, qf[ks], S1, 0, 0, 0);
        }
        __builtin_amdgcn_s_setprio(0);

        // causal mask: only the diagonal tile (t == qt)
        if (t == qt) {
            const int qrel0 = qw + ln31 - kv0 - 4 * hi;
            const int qrel1 = qrel0 - 32;
            #pragma unroll
            for (int r = 0; r < 16; r++) {
                const int ro = (r & 3) + 8 * (r >> 2);
                if (ro > qrel0) S0[r] = -1e30f;
                if (ro > qrel1) S1[r] = -1e30f;
            }
        }

        // row max: in-reg tree + 1 permlane swap
        float mx = fmaxf(S0[0], S1[0]);
        #pragma unroll
        for (int r = 1; r < 16; r++) mx = fmaxf(mx, fmaxf(S0[r], S1[r]));
        float ma = mx, mb = mx;
        pl32swapf(ma, mb);
        float rm = fmaxf(ma, mb);

        // defer-max rescale (THR=8 in log2 units)
        if (__any(rm > mrun + 8.f)) {
            float nm = fmaxf(mrun, rm);
            float corr = __builtin_amdgcn_exp2f(mrun - nm);
            mrun = nm; ls *= corr;
            #pragma unroll
            for (int r = 0; r < 16; r++) { OT0[r] *= corr; OT1[r] *= corr; }
        }

        // P = exp2(S - m) in place (bare v_exp_f32); per-lane half-row sum
        float psum = 0.f;
        #pragma unroll
        for (int r = 0; r < 16; r++) {
            S0[r] = __builtin_amdgcn_exp2f(S0[r] - mrun); psum += S0[r];
            S1[r] = __builtin_amdgcn_exp2f(S1[r] - mrun); psum += S1[r];
        }
        ls += psum;

        // build P B-fragments in-register (T12, m214-verified ordering)
        short8 pf[4];
        {
            unsigned int wa, wb, wc, wd;
            wa = cvtpk_bf16(S0[0], S0[1]);   wb = cvtpk_bf16(S0[4], S0[5]);
            pl32swap(wa, wb);
            wc = cvtpk_bf16(S0[2], S0[3]);   wd = cvtpk_bf16(S0[6], S0[7]);
            pl32swap(wc, wd);
            union { unsigned int u[4]; short8 s; } w0 = {{wa, wc, wb, wd}};
            pf[0] = w0.s;

            wa = cvtpk_bf16(S0[8], S0[9]);   wb = cvtpk_bf16(S0[12], S0[13]);
            pl32swap(wa, wb);
            wc = cvtpk_bf16(S0[10], S0[11]); wd = cvtpk_bf16(S0[14], S0[15]);
            pl32swap(wc, wd);
            union { unsigned int u[4]; short8 s; } w1 = {{wa, wc, wb, wd}};
            pf[1] = w1.s;

            wa = cvtpk_bf16(S1[0], S1[1]);   wb = cvtpk_bf16(S1[4], S1[5]);
            pl32swap(wa, wb);
            wc = cvtpk_bf16(S1[2], S1[3]);   wd = cvtpk_bf16(S1[6], S1[7]);
            pl32swap(wc, wd);
            union { unsigned int u[4]; short8 s; } w2 = {{wa, wc, wb, wd}};
            pf[2] = w2.s;

            wa = cvtpk_bf16(S1[8], S1[9]);   wb = cvtpk_bf16(S1[12], S1[13]);
            pl32swap(wa, wb);
            wc = cvtpk_bf16(S1[10], S1[11]); wd = cvtpk_bf16(S1[14], S1[15]);
            pl32swap(wc, wd);
            union { unsigned int u[4]; short8 s; } w3 = {{wa, wc, wb, wd}};
            pf[3] = w3.s;
        }

        // O^T += V^T . P  (A = V^T from subtiled Vt, B = P in-reg; XOR-swz reads)
        __builtin_amdgcn_s_setprio(1);
        #pragma unroll
        for (int ks2 = 0; ks2 < 4; ks2++) {
            int slot = (ks2 * 2 + hi) * 64;
            int r0u = slot + ln31;
            int r1u = slot + 32 + ln31;
            short8 va0 = *(const short8*)&vb[(r0u ^ rsw) * 8];
            short8 va1 = *(const short8*)&vb[(r1u ^ rsw) * 8];
            OT0 = __builtin_amdgcn_mfma_f32_32x32x16_bf16(va0, pf[ks2], OT0, 0, 0, 0);
            OT1 = __builtin_amdgcn_mfma_f32_32x32x16_bf16(va1, pf[ks2], OT1, 0, 0, 0);
        }
        __builtin_amdgcn_s_setprio(0);
    }

    // epilogue
    float la = ls, lb = ls;
    pl32swapf(la, lb);
    const float lrow = la + lb;
    const int qrow_l = wave * 32 + ln31;
    if (qt >= 16) {
        // partial: unnormalized O (bf16) + m,l (f32)
        const int rec = (bh * 16 + (qt - 16)) * 2 + cch;
        unsigned short* po = partO + (size_t)rec * 4096;
        if (hi == 0) {
            ml[(rec * 64 + qrow_l) * 2]     = mrun;
            ml[(rec * 64 + qrow_l) * 2 + 1] = lrow;
        }
        #pragma unroll
        for (int r = 0; r < 16; r++) {
            const int d0 = (r & 3) + 8 * (r >> 2) + 4 * hi;
            po[qrow_l * 64 + d0]      = f2bf(OT0[r]);
            po[qrow_l * 64 + 32 + d0] = f2bf(OT1[r]);
        }
    } else {
        float inv = 1.0f / lrow;
        const int qrow = qw + ln31;
        const size_t base = (size_t)(b * SL + qrow) * DM + h * DKH;
        #pragma unroll
        for (int r = 0; r < 16; r++) {
            const int d0 = (r & 3) + 8 * (r >> 2) + 4 * hi;
            O[base + d0]      = f2bf(OT0[r] * inv);
            O[base + 32 + d0] = f2bf(OT1[r] * inv);
        }
    }
}

// ---------------- split-KV combine: 2 partials -> final -----------------------
__global__ __launch_bounds__(256) void combine_kernel(
    const unsigned short* __restrict__ partO,
    const float* __restrict__ ml,
    unsigned short* __restrict__ O)
{
    const int gi = blockIdx.x * 8 + (threadIdx.x >> 5);   // row id 0..32767
    const int ln = threadIdx.x & 31;
    const int bh = gi >> 10, rem = gi & 1023;
    const int qtl = rem >> 6, row = rem & 63;
    const int qt = 16 + qtl;
    const int rec0 = (bh * 16 + qtl) * 2;
    const float m0 = ml[(rec0 * 64 + row) * 2];
    const float l0 = ml[(rec0 * 64 + row) * 2 + 1];
    const float m1 = ml[((rec0 + 1) * 64 + row) * 2];
    const float l1 = ml[((rec0 + 1) * 64 + row) * 2 + 1];
    const float M  = fmaxf(m0, m1);
    const float w0 = exp2f(m0 - M), w1 = exp2f(m1 - M);
    const float inv = 1.0f / (w0 * l0 + w1 * l1);
    const unsigned int u0 = *(const unsigned int*)&partO[(size_t)rec0 * 4096 + row * 64 + ln * 2];
    const unsigned int u1 = *(const unsigned int*)&partO[(size_t)(rec0 + 1) * 4096 + row * 64 + ln * 2];
    const float a0 = __uint_as_float(u0 << 16);
    const float b0 = __uint_as_float(u0 & 0xFFFF0000u);
    const float a1 = __uint_as_float(u1 << 16);
    const float b1 = __uint_as_float(u1 & 0xFFFF0000u);
    const float oa = (a0 * w0 + a1 * w1) * inv;
    const float ob = (b0 * w0 + b1 * w1) * inv;
    const unsigned int pack = (unsigned int)f2bf(oa) | ((unsigned int)f2bf(ob) << 16);
    const int b = bh >> 4, h = bh & 15;
    const size_t base = (size_t)(b * SL + qt * 64 + row) * DM + h * DKH;
    *(unsigned int*)&O[base + ln * 2] = pack;
}

// ---------------- launch -------------------------------------------------------
extern "C" void kernel_launch(void* const* d_in, const int* in_sizes, int n_in,
                              void* d_out, int out_size, void* d_ws, size_t ws_size,
                              hipStream_t stream)
{
    const float* x  = (const float*)d_in[0];
    const float* wq = (const float*)d_in[1];
    const float* wk = (const float*)d_in[2];
    const float* wv = (const float*)d_in[3];
    const float* wo = (const float*)d_in[4];
    char* ws = (char*)d_ws;
    unsigned short* xb  = (unsigned short*)(ws);                        // 8MB
    unsigned short* wqb = (unsigned short*)(ws + (8ll  << 20));         // 2MB (wq,wk,wv contiguous)
    unsigned short* wkb = (unsigned short*)(ws + (10ll << 20));
    unsigned short* wvb = (unsigned short*)(ws + (12ll << 20));
    unsigned short* wob = (unsigned short*)(ws + (14ll << 20));
    unsigned short* Qb  = (unsigned short*)(ws + (16ll << 20));         // 8MB each
    unsigned short* Kb  = (unsigned short*)(ws + (24ll << 20));
    unsigned short* Vb  = (unsigned short*)(ws + (32ll << 20));
    unsigned short* Abf = (unsigned short*)(ws + (40ll << 20));         // 8MB
    // attn scratch reuses [0,10MB): dead after the QKV GEMM consumes xb/wqb
    unsigned short* partO = (unsigned short*)(ws);                      // 8MB (1024 recs x 8KB)
    float*          mlbuf = (float*)(ws + (8ll << 20));                 // 512KB
    float* out = (float*)d_out;

    convert_kernel<<<dim3(8192), dim3(256), 0, stream>>>(
        x, wq, wk, wv, wo, xb, wqb, wkb, wvb, wob);

    // fused QKV projection: N = 3072 (wqb/wkb/wvb contiguous)
    gemm_bt<<<dim3(24, 32), dim3(256), 0, stream>>>(xb, wqb, Qb, Kb, Vb);

    // split-KV attention: 48 items x 32 bh, LPT-ordered static grid
    attn_kernel<<<dim3(1536), dim3(128), 0, stream>>>(Qb, Kb, Vb, Abf, partO, mlbuf);
    combine_kernel<<<dim3(4096), dim3(256), 0, stream>>>(partO, mlbuf, Abf);

    // output projection -> fp32 d_out (64x128 tiles, 512 blocks)
    gemm_o<<<dim3(8, 64), dim3(256), 0, stream>>>(Abf, wob, out);
}